// Round 5
// baseline (373.400 us; speedup 1.0000x reference)
//
#include <hip/hip_runtime.h>
#include <math.h>

typedef unsigned short u16;
typedef __bf16 bf16x8 __attribute__((ext_vector_type(8)));
typedef float f32x4 __attribute__((ext_vector_type(4)));
typedef short s16x8 __attribute__((ext_vector_type(8)));
typedef short s16x4 __attribute__((ext_vector_type(4)));

__device__ __forceinline__ float b2f(u16 u) {
    union { unsigned i; float f; } c; c.i = ((unsigned)u) << 16; return c.f;
}
__device__ __forceinline__ u16 f2b(float f) {
    union { float f; unsigned i; } c; c.f = f;
    return (u16)((c.i + 0x7fffu + ((c.i >> 16) & 1u)) >> 16);
}
__device__ __forceinline__ float gelu_f(float v) {
    return 0.5f * v * (1.0f + erff(v * 0.70710678118654752f));
}
__device__ __forceinline__ void async_cp16(const u16* g, u16* l) {
    __builtin_amdgcn_global_load_lds((const __attribute__((address_space(1))) void*)g,
                                     (__attribute__((address_space(3))) void*)l, 16, 0, 0);
}

// ======== plain GEMM (fold kernels only), BK=64, 128x(128*SUBN) tiles ========
#define BK 64
template<int SUBN>
__global__ __launch_bounds__(256, 2)
void gemm_bt(const u16* __restrict__ A0, const u16* __restrict__ A1,
             const u16* __restrict__ W0, const u16* __restrict__ W1,
             const float* __restrict__ B0, const float* __restrict__ B1,
             void* __restrict__ O0v, void* __restrict__ O1v,
             int lda, int K, int halfBlocks, int ldo0, int ldo1,
             int mode0, int mode1)
{
    __shared__ u16 sA[128 * BK];
    __shared__ u16 sW[SUBN * 128 * BK];

    const int bx = blockIdx.x, by = blockIdx.y;
    const int half = (bx >= halfBlocks) ? 1 : 0;
    const int bxl = bx - half * halfBlocks;
    const u16* A = (half ? A1 : A0) + (size_t)by * 128 * lda;
    const u16* W = (half ? W1 : W0) + (size_t)bxl * (128 * SUBN) * K;
    const float* bias = half ? B1 : B0;
    void* outv = half ? O1v : O0v;
    const int ldo = half ? ldo1 : ldo0;
    const int mode = half ? mode1 : mode0;

    const int tid = threadIdx.x;
    const int lane = tid & 63;
    const int wave = tid >> 6;
    const int wm = (wave >> 1) * 64;
    const int wn = (wave & 1) * 64;
    const int fc = lane & 15;
    const int quad = lane >> 4;

    int pr[4], pc[4];
#pragma unroll
    for (int c = 0; c < 4; ++c) {
        const int p = tid + 256 * c;
        pr[c] = p >> 3;
        pc[c] = ((p & 7) - (pr[c] & 7)) & 7;
    }

    f32x4 acc[4][4 * SUBN];
#pragma unroll
    for (int i = 0; i < 4; ++i)
#pragma unroll
        for (int j = 0; j < 4 * SUBN; ++j)
            acc[i][j] = f32x4{0.f, 0.f, 0.f, 0.f};

    for (int k0 = 0; k0 < K; k0 += BK) {
#pragma unroll
        for (int c = 0; c < 4; ++c)
            async_cp16(A + (size_t)pr[c] * lda + k0 + pc[c] * 8, &sA[(tid + 256 * c) * 8]);
#pragma unroll
        for (int sub = 0; sub < SUBN; ++sub)
#pragma unroll
            for (int c = 0; c < 4; ++c)
                async_cp16(W + (size_t)(sub * 128 + pr[c]) * K + k0 + pc[c] * 8,
                           &sW[(sub * 1024 + tid + 256 * c) * 8]);
        __syncthreads();

#pragma unroll
        for (int kk = 0; kk < 2; ++kk) {
            bf16x8 af[4];
#pragma unroll
            for (int i = 0; i < 4; ++i) {
                const int ar = wm + i * 16 + fc;
                af[i] = *(const bf16x8*)&sA[(ar * 8 + ((kk * 4 + quad + (ar & 7)) & 7)) * 8];
            }
#pragma unroll
            for (int sub = 0; sub < SUBN; ++sub) {
#pragma unroll
                for (int j = 0; j < 4; ++j) {
                    const int wr = wn + j * 16 + fc;
                    bf16x8 wf = *(const bf16x8*)&sW[(sub * 1024 + wr * 8 + ((kk * 4 + quad + (wr & 7)) & 7)) * 8];
#pragma unroll
                    for (int i = 0; i < 4; ++i)
                        acc[i][sub * 4 + j] =
                            __builtin_amdgcn_mfma_f32_16x16x32_bf16(af[i], wf, acc[i][sub * 4 + j], 0, 0, 0);
                }
            }
        }
        __syncthreads();
    }

#pragma unroll
    for (int sub = 0; sub < SUBN; ++sub) {
#pragma unroll
        for (int j = 0; j < 4; ++j) {
            const int colh = bxl * (128 * SUBN) + sub * 128 + wn + j * 16 + fc;
            const float bv = bias[colh];
#pragma unroll
            for (int i = 0; i < 4; ++i) {
#pragma unroll
                for (int r = 0; r < 4; ++r) {
                    const int row = by * 128 + wm + i * 16 + quad * 4 + r;
                    const float v = acc[i][sub * 4 + j][r] + bv;
                    if (mode == 1)
                        ((float*)outv)[(size_t)row * ldo + colh] = 1.0f / (1.0f + expf(-v));
                    else
                        ((u16*)outv)[(size_t)row * ldo + colh] = f2b(v);
                }
            }
        }
    }
}

// ======== GEMM + fused row-LayerNorm epilogue ========
// Block: 64 rows x (64*CT) cols = FULL row span of one output half; BK=32.
// 4 waves, wave covers all 64 rows x CT*16 cols. acc[4][CT].
// mode 0: bf16 = LN(v)*g+beta        (G1: comb halves)
// mode 1: bf16 = gelu(LN(v)*g+beta)  (G2 m1-half: h)
// mode 2: f32  = sigmoid(v), no LN   (G2 gate-half)
// mode 3: f32  = gelu(LN(v)*g+beta), + attn:=1.0 (G3: fused)
template<int CT>
__global__ __launch_bounds__(256, 2)
void gemm_ln(const u16* __restrict__ A0, const u16* __restrict__ A1,
             const u16* __restrict__ W0, const u16* __restrict__ W1,
             const float* __restrict__ B0, const float* __restrict__ B1,
             const float* __restrict__ G0, const float* __restrict__ G1,
             const float* __restrict__ Be0, const float* __restrict__ Be1,
             void* __restrict__ O0v, void* __restrict__ O1v,
             int lda, int K, int halfBlocks, int ldo0, int ldo1,
             int mode0, int mode1, float* attn1, float* attn2)
{
    constexpr int TN = 64 * CT;            // 512 (CT=8) or 256 (CT=4)
    __shared__ u16 sA[64 * 32];            // 4 KB
    __shared__ u16 sW[TN * 32];            // 32 / 16 KB
    __shared__ float sred[2][4][64];       // 2 KB

    const int bx = blockIdx.x, by = blockIdx.y;
    const int half = (bx >= halfBlocks) ? 1 : 0;
    const u16* A = (half ? A1 : A0) + (size_t)by * 64 * lda;
    const u16* W = half ? W1 : W0;
    const float* bias = half ? B1 : B0;
    const float* gain = half ? G1 : G0;
    const float* beta = half ? Be1 : Be0;
    void* outv = half ? O1v : O0v;
    const int ldo = half ? ldo1 : ldo0;
    const int mode = half ? mode1 : mode0;

    const int tid = threadIdx.x;
    const int lane = tid & 63;
    const int wave = tid >> 6;
    const int wn = wave * (CT * 16);
    const int fc = lane & 15;
    const int quad = lane >> 4;

    // A: 256 chunks -> 1/thread; W: TN*4 chunks -> CT/thread.  R2-proven swizzle:
    // slot p holds (r = p>>2, k8 = ((p&3)-(r>>1))&3); read slot = r*4+((quad+(r>>1))&3).
    const int ra = tid >> 2, ca = ((tid & 3) - (ra >> 1)) & 3;
    int rw[CT], cw[CT];
#pragma unroll
    for (int c = 0; c < CT; ++c) {
        const int p = tid + 256 * c;
        rw[c] = p >> 2;
        cw[c] = ((p & 3) - (rw[c] >> 1)) & 3;
    }

    f32x4 acc[4][CT];
#pragma unroll
    for (int i = 0; i < 4; ++i)
#pragma unroll
        for (int j = 0; j < CT; ++j)
            acc[i][j] = f32x4{0.f, 0.f, 0.f, 0.f};

    for (int k0 = 0; k0 < K; k0 += 32) {
        async_cp16(A + (size_t)ra * lda + k0 + ca * 8, &sA[tid * 8]);
#pragma unroll
        for (int c = 0; c < CT; ++c)
            async_cp16(W + (size_t)rw[c] * K + k0 + cw[c] * 8, &sW[(tid + 256 * c) * 8]);
        __syncthreads();

        bf16x8 af[4];
#pragma unroll
        for (int i = 0; i < 4; ++i) {
            const int ar = i * 16 + fc;
            af[i] = *(const bf16x8*)&sA[(ar * 4 + ((quad + (ar >> 1)) & 3)) * 8];
        }
#pragma unroll
        for (int j = 0; j < CT; ++j) {
            const int wr = wn + j * 16 + fc;
            bf16x8 wf = *(const bf16x8*)&sW[(wr * 4 + ((quad + (wr >> 1)) & 3)) * 8];
#pragma unroll
            for (int i = 0; i < 4; ++i)
                acc[i][j] = __builtin_amdgcn_mfma_f32_16x16x32_bf16(af[i], wf, acc[i][j], 0, 0, 0);
        }
        __syncthreads();
    }

    // bias add (pre-LN value v = acc + bias[col])
#pragma unroll
    for (int j = 0; j < CT; ++j) {
        const float bv = bias[wn + j * 16 + fc];
#pragma unroll
        for (int i = 0; i < 4; ++i)
#pragma unroll
            for (int r = 0; r < 4; ++r)
                acc[i][j][r] += bv;
    }

    if (mode == 2) {                       // sigmoid, no LN
#pragma unroll
        for (int j = 0; j < CT; ++j) {
            const int col = wn + j * 16 + fc;
#pragma unroll
            for (int i = 0; i < 4; ++i)
#pragma unroll
                for (int r = 0; r < 4; ++r) {
                    const int row = by * 64 + i * 16 + quad * 4 + r;
                    ((float*)outv)[(size_t)row * ldo + col] =
                        1.0f / (1.0f + expf(-acc[i][j][r]));
                }
        }
        return;
    }

    // per-row sum/sumsq: partial over this wave's CT*16 cols, reduce over fc
#pragma unroll
    for (int i = 0; i < 4; ++i) {
#pragma unroll
        for (int r = 0; r < 4; ++r) {
            float s = 0.f, ss = 0.f;
#pragma unroll
            for (int j = 0; j < CT; ++j) {
                const float v = acc[i][j][r];
                s += v; ss += v * v;
            }
#pragma unroll
            for (int m = 1; m <= 8; m <<= 1) {
                s += __shfl_xor(s, m); ss += __shfl_xor(ss, m);
            }
            if (fc == 0) {
                const int row = i * 16 + quad * 4 + r;
                sred[0][wave][row] = s;
                sred[1][wave][row] = ss;
            }
        }
    }
    __syncthreads();

    float gv[CT], bev[CT];
#pragma unroll
    for (int j = 0; j < CT; ++j) {
        gv[j] = gain[wn + j * 16 + fc];
        bev[j] = beta[wn + j * 16 + fc];
    }

#pragma unroll
    for (int i = 0; i < 4; ++i) {
#pragma unroll
        for (int r = 0; r < 4; ++r) {
            const int rloc = i * 16 + quad * 4 + r;
            const float S = sred[0][0][rloc] + sred[0][1][rloc] + sred[0][2][rloc] + sred[0][3][rloc];
            const float SS = sred[1][0][rloc] + sred[1][1][rloc] + sred[1][2][rloc] + sred[1][3][rloc];
            const float mean = S * (1.f / TN);
            const float var = SS * (1.f / TN) - mean * mean;
            const float rs = rsqrtf(var + 1e-5f);
            const int row = by * 64 + rloc;
#pragma unroll
            for (int j = 0; j < CT; ++j) {
                const int col = wn + j * 16 + fc;
                float y = (acc[i][j][r] - mean) * rs * gv[j] + bev[j];
                if (mode != 0) y = gelu_f(y);
                if (mode == 3)
                    ((float*)outv)[(size_t)row * ldo + col] = y;
                else
                    ((u16*)outv)[(size_t)row * ldo + col] = f2b(y);
            }
        }
    }
    if (mode == 3 && tid < 64) {
        attn1[by * 64 + tid] = 1.0f;
        attn2[by * 64 + tid] = 1.0f;
    }
}

// ======== prep ========

__device__ __forceinline__ void cvt_quads(const float* __restrict__ src,
                                          u16* __restrict__ dst, int bi, int tid)
{
#pragma unroll
    for (int c = 0; c < 2; ++c) {
        const int q = bi * 512 + tid + 256 * c;
        f32x4 v = *(const f32x4*)(src + (size_t)q * 4);
        s16x4 o;
        o[0] = (short)f2b(v[0]); o[1] = (short)f2b(v[1]);
        o[2] = (short)f2b(v[2]); o[3] = (short)f2b(v[3]);
        *(s16x4*)(dst + (size_t)q * 4) = o;
    }
}

__device__ void transpose_cvt64(const float* __restrict__ src, int C,
                                u16* __restrict__ dst, int R,
                                int tr, int tc, int tid, float* sm)
{
    const int lr = tid >> 4, lc4 = (tid & 15) * 4;
#pragma unroll
    for (int m = 0; m < 4; ++m) {
        const int i = lr + m * 16;
        f32x4 v = *(const f32x4*)&src[(size_t)(tr + i) * C + tc + lc4];
#pragma unroll
        for (int mm = 0; mm < 4; ++mm) sm[i * 65 + lc4 + mm] = v[mm];
    }
    __syncthreads();
#pragma unroll
    for (int m = 0; m < 4; ++m) {
        const int j = lr + m * 16;
        s16x4 o;
#pragma unroll
        for (int mm = 0; mm < 4; ++mm)
            o[mm] = (short)f2b(sm[(size_t)(lc4 + mm) * 65 + j]);
        *(s16x4*)&dst[(size_t)(tc + j) * R + tr + lc4] = o;
    }
}

__device__ void matvec_rows(const float* __restrict__ M, const float* __restrict__ v,
                            const float* __restrict__ add1, const float* __restrict__ add2,
                            float* __restrict__ out, int r0, int tid, float* sm)
{
    for (int i = tid; i < 512; i += 256) sm[i] = v[i];
    __syncthreads();
    const int row = r0 + (tid & 63), q = tid >> 6;
    float s = 0.f;
    for (int k = q * 128; k < q * 128 + 128; k += 4) {
        f32x4 m = *(const f32x4*)&M[(size_t)row * 512 + k];
        s += m[0] * sm[k] + m[1] * sm[k + 1] + m[2] * sm[k + 2] + m[3] * sm[k + 3];
    }
    sm[512 + tid] = s;
    __syncthreads();
    if (tid < 64)
        out[r0 + tid] = sm[512 + tid] + sm[512 + tid + 64] + sm[512 + tid + 128] +
                        sm[512 + tid + 192] + add1[r0 + tid] + add2[r0 + tid];
}

__global__ __launch_bounds__(256)
void prep_cvt(const float* __restrict__ text, const float* __restrict__ num,
              const float* __restrict__ tp_w, const float* __restrict__ np_w,
              const float* __restrict__ g_w, const float* __restrict__ m1_w,
              const float* __restrict__ m2_w,
              const float* __restrict__ a1_wv, const float* __restrict__ a2_wv,
              const float* __restrict__ a1_wo, const float* __restrict__ a2_wo,
              const float* __restrict__ a1_bv, const float* __restrict__ a1_bo,
              const float* __restrict__ a2_bv, const float* __restrict__ a2_bo,
              const float* __restrict__ tp_b, const float* __restrict__ np_b,
              u16* __restrict__ EMBc, u16* __restrict__ Wbig,
              u16* __restrict__ g_bf, u16* __restrict__ m1_bf, u16* __restrict__ m2_bf,
              u16* __restrict__ a1_wvT, u16* __restrict__ a2_wvT,
              u16* __restrict__ tp_wT, u16* __restrict__ np_wT,
              u16* __restrict__ a1_wo_bf, u16* __restrict__ a2_wo_bf,
              float* __restrict__ w1, float* __restrict__ w2,
              float* __restrict__ zb)
{
    __shared__ float smem[64 * 65];
    const int b = blockIdx.x, tid = threadIdx.x;
    if (b < 4096) {                       // EMBc[row,0:256]=text, [256:512]=num
#pragma unroll
        for (int c = 0; c < 2; ++c) {
            const int q = b * 512 + tid + 256 * c;
            const int e = q * 4, row = e >> 9, col = e & 511;
            const float* src = (col < 256) ? text + (size_t)row * 256 + col
                                           : num + (size_t)row * 256 + (col - 256);
            f32x4 v = *(const f32x4*)src;
            s16x4 o;
            o[0] = (short)f2b(v[0]); o[1] = (short)f2b(v[1]);
            o[2] = (short)f2b(v[2]); o[3] = (short)f2b(v[3]);
            *(s16x4*)(EMBc + e) = o;
        }
    } else if (b < 4352) { cvt_quads(g_w, g_bf, b - 4096, tid); }
    else if (b < 4608) { cvt_quads(m1_w, m1_bf, b - 4352, tid); }
    else if (b < 4672) { cvt_quads(m2_w, m2_bf, b - 4608, tid); }
    else if (b < 4736) {                  // np_w -> Wbig[0:512, 256:512]
#pragma unroll
        for (int c = 0; c < 2; ++c) {
            const int q = (b - 4672) * 512 + tid + 256 * c;
            const int e = q * 4, row = e >> 8, col = e & 255;
            f32x4 v = *(const f32x4*)(np_w + e);
            s16x4 o;
            o[0] = (short)f2b(v[0]); o[1] = (short)f2b(v[1]);
            o[2] = (short)f2b(v[2]); o[3] = (short)f2b(v[3]);
            *(s16x4*)(Wbig + (size_t)row * 512 + 256 + col) = o;
        }
    } else if (b < 4800) {                // tp_w -> Wbig[512:1024, 0:256]
#pragma unroll
        for (int c = 0; c < 2; ++c) {
            const int q = (b - 4736) * 512 + tid + 256 * c;
            const int e = q * 4, row = e >> 8, col = e & 255;
            f32x4 v = *(const f32x4*)(tp_w + e);
            s16x4 o;
            o[0] = (short)f2b(v[0]); o[1] = (short)f2b(v[1]);
            o[2] = (short)f2b(v[2]); o[3] = (short)f2b(v[3]);
            *(s16x4*)(Wbig + (size_t)(512 + row) * 512 + col) = o;
        }
    } else if (b < 4864) {
        const int t = b - 4800;
        transpose_cvt64(a1_wv, 512, a1_wvT, 512, (t >> 3) * 64, (t & 7) * 64, tid, smem);
    } else if (b < 4928) {
        const int t = b - 4864;
        transpose_cvt64(a2_wv, 512, a2_wvT, 512, (t >> 3) * 64, (t & 7) * 64, tid, smem);
    } else if (b < 4960) {
        const int t = b - 4928;
        transpose_cvt64(tp_w, 256, tp_wT, 512, (t >> 2) * 64, (t & 3) * 64, tid, smem);
    } else if (b < 4992) {
        const int t = b - 4960;
        transpose_cvt64(np_w, 256, np_wT, 512, (t >> 2) * 64, (t & 3) * 64, tid, smem);
    } else if (b < 5120) { cvt_quads(a1_wo, a1_wo_bf, b - 4992, tid); }
    else if (b < 5248) { cvt_quads(a2_wo, a2_wo_bf, b - 5120, tid); }
    else if (b < 5256) {
        matvec_rows(a1_wo, a1_bv, a1_bo, np_b, w1, (b - 5248) * 64, tid, smem);
    } else if (b < 5264) {
        matvec_rows(a2_wo, a2_bv, a2_bo, tp_b, w2, (b - 5256) * 64, tid, smem);
    } else {
        *(f32x4*)&zb[tid * 4] = f32x4{0.f, 0.f, 0.f, 0.f};
    }
}

__global__ __launch_bounds__(256)
void prep_bias(const u16* __restrict__ M1, const u16* __restrict__ M2,
               const float* __restrict__ tp_b, const float* __restrict__ np_b,
               const float* __restrict__ w1, const float* __restrict__ w2,
               float* __restrict__ bbig)
{
    __shared__ float sm[768];
    const int b = blockIdx.x, tid = threadIdx.x;
    const int side = b >> 3, r0 = (b & 7) * 64;
    const u16* M = side ? M2 : M1;
    const float* v = side ? np_b : tp_b;
    const float* w = side ? w2 : w1;
    float* out = bbig + side * 512;
    for (int i = tid; i < 512; i += 256) sm[i] = v[i];
    __syncthreads();
    const int row = r0 + (tid & 63), q = tid >> 6;
    float s = 0.f;
    for (int k = q * 128; k < q * 128 + 128; k += 8) {
        s16x8 m = *(const s16x8*)&M[(size_t)row * 512 + k];
#pragma unroll
        for (int j = 0; j < 8; ++j) s += b2f((u16)m[j]) * sm[k + j];
    }
    sm[512 + tid] = s;
    __syncthreads();
    if (tid < 64)
        out[r0 + tid] = sm[512 + tid] + sm[512 + tid + 64] + sm[512 + tid + 128] +
                        sm[512 + tid + 192] + w[r0 + tid];
}

extern "C" void kernel_launch(void* const* d_in, const int* in_sizes, int n_in,
                              void* d_out, int out_size, void* d_ws, size_t ws_size,
                              hipStream_t stream)
{
    const float* text  = (const float*)d_in[0];
    const float* num   = (const float*)d_in[1];
    const float* tp_w  = (const float*)d_in[2];
    const float* tp_b  = (const float*)d_in[3];
    const float* np_w  = (const float*)d_in[4];
    const float* np_b  = (const float*)d_in[5];
    const float* a1_wv = (const float*)d_in[8];
    const float* a1_bv = (const float*)d_in[11];
    const float* a1_wo = (const float*)d_in[12];
    const float* a1_bo = (const float*)d_in[13];
    const float* a2_wv = (const float*)d_in[16];
    const float* a2_bv = (const float*)d_in[19];
    const float* a2_wo = (const float*)d_in[20];
    const float* a2_bo = (const float*)d_in[21];
    const float* n1_g  = (const float*)d_in[22];
    const float* n1_b  = (const float*)d_in[23];
    const float* n2_g  = (const float*)d_in[24];
    const float* n2_b  = (const float*)d_in[25];
    const float* g_w   = (const float*)d_in[26];
    const float* g_b   = (const float*)d_in[27];
    const float* m1_w  = (const float*)d_in[28];
    const float* m1_b  = (const float*)d_in[29];
    const float* ln1_g = (const float*)d_in[30];
    const float* ln1_b = (const float*)d_in[31];
    const float* m2_w  = (const float*)d_in[32];
    const float* m2_b  = (const float*)d_in[33];
    const float* ln2_g = (const float*)d_in[34];
    const float* ln2_b = (const float*)d_in[35];

    float* outp = (float*)d_out;
    char* ob = (char*)d_out;
    char* ws = (char*)d_ws;
    const size_t KB = 1024, MB = 1048576;

    // ws: comb [0,32MB), h [32,48MB), weight scratch [48MB,...)
    u16* comb = (u16*)ws;                            // [16384 x 1024] bf16
    u16* h    = (u16*)(ws + 32 * MB);                // [16384 x 512] bf16
    char* sc  = ws + 48 * MB;
    u16* Wbig     = (u16*)(sc);                      // 1 MB [1024x512]
    u16* g_bf     = (u16*)(sc + 1 * MB);             // 1 MB [512x1024]
    u16* m1_bf    = (u16*)(sc + 2 * MB);             // 1 MB [512x1024]
    u16* m2_bf    = (u16*)(sc + 3 * MB);             // 256 KB [256x512]
    u16* a1_wvT   = (u16*)(sc + 3 * MB + 256 * KB);  // 512 KB
    u16* a2_wvT   = (u16*)(sc + 3 * MB + 768 * KB);  // 512 KB
    u16* tp_wT    = (u16*)(sc + 4 * MB + 256 * KB);  // 256 KB [256x512]
    u16* np_wT    = (u16*)(sc + 4 * MB + 512 * KB);  // 256 KB
    u16* a1_wo_bf = (u16*)(sc + 4 * MB + 768 * KB);  // 512 KB
    u16* a2_wo_bf = (u16*)(sc + 5 * MB + 256 * KB);  // 512 KB
    u16* M1       = (u16*)(sc + 5 * MB + 768 * KB);  // 512 KB
    u16* M2       = (u16*)(sc + 6 * MB + 256 * KB);  // 512 KB
    float* w1     = (float*)(sc + 6 * MB + 768 * KB);
    float* w2     = w1 + 512;
    float* bbig   = w1 + 1024;
    float* zb     = w1 + 2048;
    // d_out scratch: EMBc in the dead gate byte-range [16MB,32MB)
    u16* EMBc = (u16*)(ob + 16 * MB);                // [16384 x 512] bf16

    float* gate_out = outp + (size_t)16384 * 256;    // [B,512] f32
    float* attn1 = outp + (size_t)16384 * 768;
    float* attn2 = outp + (size_t)16384 * 768 + 16384;

    dim3 blk(256);

    // P1: conversions, transposes, w1/w2, zbias
    prep_cvt<<<5265, blk, 0, stream>>>(text, num, tp_w, np_w, g_w, m1_w, m2_w,
        a1_wv, a2_wv, a1_wo, a2_wo, a1_bv, a1_bo, a2_bv, a2_bo, tp_b, np_b,
        EMBc, Wbig, g_bf, m1_bf, m2_bf, a1_wvT, a2_wvT, tp_wT, np_wT,
        a1_wo_bf, a2_wo_bf, w1, w2, zb);
    // F1: M1 = a1_wo@a1_wv ; M2 = a2_wo@a2_wv
    gemm_bt<2><<<dim3(4, 4), blk, 0, stream>>>(a1_wo_bf, a2_wo_bf, a1_wvT, a2_wvT,
        zb, zb, M1, M2, 512, 512, 2, 512, 512, 0, 0);
    // PB: bbig = [M1@tp_b + w1 | M2@np_b + w2]
    prep_bias<<<16, blk, 0, stream>>>(M1, M2, tp_b, np_b, w1, w2, bbig);
    // F2: Wbig[0:512,0:256] = M1@tp_w ; Wbig[512:,256:] = M2@np_w
    gemm_bt<2><<<dim3(2, 4), blk, 0, stream>>>(M1, M2, tp_wT, np_wT,
        zb, zb, Wbig, Wbig + (size_t)512 * 512 + 256, 512, 512, 1, 512, 512, 0, 0);
    // G1': comb = [LN(EMB@WbigL.T + bL)*n1 | LN(EMB@WbigR.T + bR)*n2]
    gemm_ln<8><<<dim3(2, 256), blk, 0, stream>>>(EMBc, EMBc,
        Wbig, Wbig + (size_t)512 * 512, bbig, bbig + 512,
        n1_g, n2_g, n1_b, n2_b, comb, comb + 512,
        512, 512, 1, 1024, 1024, 0, 0, nullptr, nullptr);
    // G2': gate = sigmoid(comb@g_w.T+g_b) f32 ; h = gelu(LN(comb@m1_w.T+m1_b)*ln1)
    gemm_ln<8><<<dim3(2, 256), blk, 0, stream>>>(comb, comb, g_bf, m1_bf,
        g_b, m1_b, ln1_g, ln1_g, ln1_b, ln1_b, gate_out, h,
        1024, 1024, 1, 512, 512, 2, 1, nullptr, nullptr);
    // G3': fused = gelu(LN(h@m2_w.T+m2_b)*ln2) f32 -> d_out; attn := 1.0
    gemm_ln<4><<<dim3(1, 256), blk, 0, stream>>>(h, h, m2_bf, m2_bf,
        m2_b, m2_b, ln2_g, ln2_g, ln2_b, ln2_b, outp, outp,
        512, 512, 1, 256, 256, 3, 3, attn1, attn2);
}

// Round 6
// 370.300 us; speedup vs baseline: 1.0084x; 1.0084x over previous
//
#include <hip/hip_runtime.h>
#include <math.h>

typedef unsigned short u16;
typedef __bf16 bf16x8 __attribute__((ext_vector_type(8)));
typedef float f32x4 __attribute__((ext_vector_type(4)));
typedef short s16x8 __attribute__((ext_vector_type(8)));
typedef short s16x4 __attribute__((ext_vector_type(4)));

__device__ __forceinline__ float b2f(u16 u) {
    union { unsigned i; float f; } c; c.i = ((unsigned)u) << 16; return c.f;
}
__device__ __forceinline__ u16 f2b(float f) {
    union { float f; unsigned i; } c; c.f = f;
    return (u16)((c.i + 0x7fffu + ((c.i >> 16) & 1u)) >> 16);
}
__device__ __forceinline__ float gelu_f(float v) {
    return 0.5f * v * (1.0f + erff(v * 0.70710678118654752f));
}
__device__ __forceinline__ void async_cp16(const u16* g, u16* l) {
    __builtin_amdgcn_global_load_lds((const __attribute__((address_space(1))) void*)g,
                                     (__attribute__((address_space(3))) void*)l, 16, 0, 0);
}

// ======== plain GEMM (fold kernels only), BK=64, 128x(128*SUBN) tiles ========
#define BK 64
template<int SUBN>
__global__ __launch_bounds__(256, 2)
void gemm_bt(const u16* __restrict__ A0, const u16* __restrict__ A1,
             const u16* __restrict__ W0, const u16* __restrict__ W1,
             const float* __restrict__ B0, const float* __restrict__ B1,
             void* __restrict__ O0v, void* __restrict__ O1v,
             int lda, int K, int halfBlocks, int ldo0, int ldo1,
             int mode0, int mode1)
{
    __shared__ u16 sA[128 * BK];
    __shared__ u16 sW[SUBN * 128 * BK];

    const int bx = blockIdx.x, by = blockIdx.y;
    const int half = (bx >= halfBlocks) ? 1 : 0;
    const int bxl = bx - half * halfBlocks;
    const u16* A = (half ? A1 : A0) + (size_t)by * 128 * lda;
    const u16* W = (half ? W1 : W0) + (size_t)bxl * (128 * SUBN) * K;
    const float* bias = half ? B1 : B0;
    void* outv = half ? O1v : O0v;
    const int ldo = half ? ldo1 : ldo0;
    const int mode = half ? mode1 : mode0;

    const int tid = threadIdx.x;
    const int lane = tid & 63;
    const int wave = tid >> 6;
    const int wm = (wave >> 1) * 64;
    const int wn = (wave & 1) * 64;
    const int fc = lane & 15;
    const int quad = lane >> 4;

    int pr[4], pc[4];
#pragma unroll
    for (int c = 0; c < 4; ++c) {
        const int p = tid + 256 * c;
        pr[c] = p >> 3;
        pc[c] = ((p & 7) - (pr[c] & 7)) & 7;
    }

    f32x4 acc[4][4 * SUBN];
#pragma unroll
    for (int i = 0; i < 4; ++i)
#pragma unroll
        for (int j = 0; j < 4 * SUBN; ++j)
            acc[i][j] = f32x4{0.f, 0.f, 0.f, 0.f};

    for (int k0 = 0; k0 < K; k0 += BK) {
#pragma unroll
        for (int c = 0; c < 4; ++c)
            async_cp16(A + (size_t)pr[c] * lda + k0 + pc[c] * 8, &sA[(tid + 256 * c) * 8]);
#pragma unroll
        for (int sub = 0; sub < SUBN; ++sub)
#pragma unroll
            for (int c = 0; c < 4; ++c)
                async_cp16(W + (size_t)(sub * 128 + pr[c]) * K + k0 + pc[c] * 8,
                           &sW[(sub * 1024 + tid + 256 * c) * 8]);
        __syncthreads();

#pragma unroll
        for (int kk = 0; kk < 2; ++kk) {
            bf16x8 af[4];
#pragma unroll
            for (int i = 0; i < 4; ++i) {
                const int ar = wm + i * 16 + fc;
                af[i] = *(const bf16x8*)&sA[(ar * 8 + ((kk * 4 + quad + (ar & 7)) & 7)) * 8];
            }
#pragma unroll
            for (int sub = 0; sub < SUBN; ++sub) {
#pragma unroll
                for (int j = 0; j < 4; ++j) {
                    const int wr = wn + j * 16 + fc;
                    bf16x8 wf = *(const bf16x8*)&sW[(sub * 1024 + wr * 8 + ((kk * 4 + quad + (wr & 7)) & 7)) * 8];
#pragma unroll
                    for (int i = 0; i < 4; ++i)
                        acc[i][sub * 4 + j] =
                            __builtin_amdgcn_mfma_f32_16x16x32_bf16(af[i], wf, acc[i][sub * 4 + j], 0, 0, 0);
                }
            }
        }
        __syncthreads();
    }

#pragma unroll
    for (int sub = 0; sub < SUBN; ++sub) {
#pragma unroll
        for (int j = 0; j < 4; ++j) {
            const int colh = bxl * (128 * SUBN) + sub * 128 + wn + j * 16 + fc;
            const float bv = bias[colh];
#pragma unroll
            for (int i = 0; i < 4; ++i) {
#pragma unroll
                for (int r = 0; r < 4; ++r) {
                    const int row = by * 128 + wm + i * 16 + quad * 4 + r;
                    const float v = acc[i][sub * 4 + j][r] + bv;
                    if (mode == 1)
                        ((float*)outv)[(size_t)row * ldo + colh] = 1.0f / (1.0f + expf(-v));
                    else
                        ((u16*)outv)[(size_t)row * ldo + colh] = f2b(v);
                }
            }
        }
    }
}

// ======== GEMM + fused row-LayerNorm epilogue, 512-thread blocks ========
// Block: 128 rows x TN cols (TN = CWT*64), full row span of one output half.
// 8 waves = 2 row-groups x 4 col-waves; wave tile 64 x (CWT*16); BK=32.
// mode 0: bf16 = LN(v)*g+beta        (G1: comb halves)
// mode 1: bf16 = gelu(LN(v)*g+beta)  (G2 m1-half: h)
// mode 2: f32  = sigmoid(v), no LN   (G2 gate-half)
// mode 3: f32  = gelu(LN(v)*g+beta), + attn:=1.0 (G3: fused)
template<int CWT>    // 8 -> TN=512, 4 -> TN=256
__global__ __launch_bounds__(512, 2)
void gemm_ln(const u16* __restrict__ A0, const u16* __restrict__ A1,
             const u16* __restrict__ W0, const u16* __restrict__ W1,
             const float* __restrict__ B0, const float* __restrict__ B1,
             const float* __restrict__ G0, const float* __restrict__ G1p,
             const float* __restrict__ Be0, const float* __restrict__ Be1,
             void* __restrict__ O0v, void* __restrict__ O1v,
             int lda, int K, int halfBlocks, int ldo0, int ldo1,
             int mode0, int mode1, float* attn1, float* attn2)
{
    constexpr int TN = CWT * 64;
    constexpr int WC = TN / 128;           // W chunks per thread (4 or 2)
    __shared__ u16 sA[128 * 32];           // 8 KB
    __shared__ u16 sW[TN * 32];            // 32 / 16 KB
    __shared__ float sred[2][2][4][64];    // 4 KB [stat][rowgrp][colwave][row]

    const int bx = blockIdx.x, by = blockIdx.y;
    const int half = (bx >= halfBlocks) ? 1 : 0;
    const u16* A = (half ? A1 : A0) + (size_t)by * 128 * lda;
    const u16* W = half ? W1 : W0;
    const float* bias = half ? B1 : B0;
    const float* gain = half ? G1p : G0;
    const float* beta = half ? Be1 : Be0;
    void* outv = half ? O1v : O0v;
    const int ldo = half ? ldo1 : ldo0;
    const int mode = half ? mode1 : mode0;

    const int tid = threadIdx.x;
    const int lane = tid & 63;
    const int wave = tid >> 6;             // 0..7
    const int rg = wave >> 2;              // row group (64 rows each)
    const int cw = wave & 3;               // col wave
    const int wm = rg * 64;
    const int wn = cw * (CWT * 16);
    const int fc = lane & 15;
    const int quad = lane >> 4;

    // R2-proven swizzle (BK=32, 4 chunks/row): slot p holds
    // (r = p>>2, k8 = ((p&3)-(r>>1))&3); frag read slot = r*4 + ((quad+(r>>1))&3).
    const int ra = tid >> 2, ca = ((tid & 3) - (ra >> 1)) & 3;     // A: 1 chunk/thread
    int rw[WC], ck[WC];
#pragma unroll
    for (int c = 0; c < WC; ++c) {
        const int p = tid + 512 * c;
        rw[c] = p >> 2;
        ck[c] = ((p & 3) - (rw[c] >> 1)) & 3;
    }

    f32x4 acc[4][CWT];
#pragma unroll
    for (int i = 0; i < 4; ++i)
#pragma unroll
        for (int j = 0; j < CWT; ++j)
            acc[i][j] = f32x4{0.f, 0.f, 0.f, 0.f};

    for (int k0 = 0; k0 < K; k0 += 32) {
        async_cp16(A + (size_t)ra * lda + k0 + ca * 8, &sA[tid * 8]);
#pragma unroll
        for (int c = 0; c < WC; ++c)
            async_cp16(W + (size_t)rw[c] * K + k0 + ck[c] * 8, &sW[(tid + 512 * c) * 8]);
        __syncthreads();

        bf16x8 af[4];
#pragma unroll
        for (int i = 0; i < 4; ++i) {
            const int ar = wm + i * 16 + fc;
            af[i] = *(const bf16x8*)&sA[(ar * 4 + ((quad + (ar >> 1)) & 3)) * 8];
        }
#pragma unroll
        for (int j = 0; j < CWT; ++j) {
            const int wr = wn + j * 16 + fc;
            bf16x8 wf = *(const bf16x8*)&sW[(wr * 4 + ((quad + (wr >> 1)) & 3)) * 8];
#pragma unroll
            for (int i = 0; i < 4; ++i)
                acc[i][j] = __builtin_amdgcn_mfma_f32_16x16x32_bf16(af[i], wf, acc[i][j], 0, 0, 0);
        }
        __syncthreads();
    }

    // bias add
#pragma unroll
    for (int j = 0; j < CWT; ++j) {
        const float bv = bias[wn + j * 16 + fc];
#pragma unroll
        for (int i = 0; i < 4; ++i)
#pragma unroll
            for (int r = 0; r < 4; ++r)
                acc[i][j][r] += bv;
    }

    if (mode == 2) {                       // sigmoid, no LN
#pragma unroll
        for (int j = 0; j < CWT; ++j) {
            const int col = wn + j * 16 + fc;
#pragma unroll
            for (int i = 0; i < 4; ++i)
#pragma unroll
                for (int r = 0; r < 4; ++r) {
                    const int row = by * 128 + wm + i * 16 + quad * 4 + r;
                    ((float*)outv)[(size_t)row * ldo + col] =
                        1.0f / (1.0f + expf(-acc[i][j][r]));
                }
        }
        return;
    }

    // per-row partials over this wave's CWT*16 cols; reduce across fc
#pragma unroll
    for (int i = 0; i < 4; ++i) {
#pragma unroll
        for (int r = 0; r < 4; ++r) {
            float s = 0.f, ss = 0.f;
#pragma unroll
            for (int j = 0; j < CWT; ++j) {
                const float v = acc[i][j][r];
                s += v; ss += v * v;
            }
#pragma unroll
            for (int m = 1; m <= 8; m <<= 1) {
                s += __shfl_xor(s, m); ss += __shfl_xor(ss, m);
            }
            if (fc == 0) {
                const int rloc = i * 16 + quad * 4 + r;
                sred[0][rg][cw][rloc] = s;
                sred[1][rg][cw][rloc] = ss;
            }
        }
    }
    __syncthreads();

    float gv[CWT], bev[CWT];
#pragma unroll
    for (int j = 0; j < CWT; ++j) {
        gv[j] = gain[wn + j * 16 + fc];
        bev[j] = beta[wn + j * 16 + fc];
    }

#pragma unroll
    for (int i = 0; i < 4; ++i) {
#pragma unroll
        for (int r = 0; r < 4; ++r) {
            const int rloc = i * 16 + quad * 4 + r;
            const float S = sred[0][rg][0][rloc] + sred[0][rg][1][rloc] +
                            sred[0][rg][2][rloc] + sred[0][rg][3][rloc];
            const float SS = sred[1][rg][0][rloc] + sred[1][rg][1][rloc] +
                             sred[1][rg][2][rloc] + sred[1][rg][3][rloc];
            const float mean = S * (1.f / TN);
            const float var = SS * (1.f / TN) - mean * mean;
            const float rs = rsqrtf(var + 1e-5f);
            const int row = by * 128 + wm + rloc;
#pragma unroll
            for (int j = 0; j < CWT; ++j) {
                const int col = wn + j * 16 + fc;
                float y = (acc[i][j][r] - mean) * rs * gv[j] + bev[j];
                if (mode != 0) y = gelu_f(y);
                if (mode == 3)
                    ((float*)outv)[(size_t)row * ldo + col] = y;
                else
                    ((u16*)outv)[(size_t)row * ldo + col] = f2b(y);
            }
        }
    }
    if (mode == 3 && tid < 128) {
        attn1[by * 128 + tid] = 1.0f;
        attn2[by * 128 + tid] = 1.0f;
    }
}

// ======== prep ========

__device__ __forceinline__ void cvt_quads(const float* __restrict__ src,
                                          u16* __restrict__ dst, int bi, int tid)
{
#pragma unroll
    for (int c = 0; c < 2; ++c) {
        const int q = bi * 512 + tid + 256 * c;
        f32x4 v = *(const f32x4*)(src + (size_t)q * 4);
        s16x4 o;
        o[0] = (short)f2b(v[0]); o[1] = (short)f2b(v[1]);
        o[2] = (short)f2b(v[2]); o[3] = (short)f2b(v[3]);
        *(s16x4*)(dst + (size_t)q * 4) = o;
    }
}

__device__ void transpose_cvt64(const float* __restrict__ src, int C,
                                u16* __restrict__ dst, int R,
                                int tr, int tc, int tid, float* sm)
{
    const int lr = tid >> 4, lc4 = (tid & 15) * 4;
#pragma unroll
    for (int m = 0; m < 4; ++m) {
        const int i = lr + m * 16;
        f32x4 v = *(const f32x4*)&src[(size_t)(tr + i) * C + tc + lc4];
#pragma unroll
        for (int mm = 0; mm < 4; ++mm) sm[i * 65 + lc4 + mm] = v[mm];
    }
    __syncthreads();
#pragma unroll
    for (int m = 0; m < 4; ++m) {
        const int j = lr + m * 16;
        s16x4 o;
#pragma unroll
        for (int mm = 0; mm < 4; ++mm)
            o[mm] = (short)f2b(sm[(size_t)(lc4 + mm) * 65 + j]);
        *(s16x4*)&dst[(size_t)(tc + j) * R + tr + lc4] = o;
    }
}

__device__ void matvec_rows(const float* __restrict__ M, const float* __restrict__ v,
                            const float* __restrict__ add1, const float* __restrict__ add2,
                            float* __restrict__ out, int r0, int tid, float* sm)
{
    for (int i = tid; i < 512; i += 256) sm[i] = v[i];
    __syncthreads();
    const int row = r0 + (tid & 63), q = tid >> 6;
    float s = 0.f;
    for (int k = q * 128; k < q * 128 + 128; k += 4) {
        f32x4 m = *(const f32x4*)&M[(size_t)row * 512 + k];
        s += m[0] * sm[k] + m[1] * sm[k + 1] + m[2] * sm[k + 2] + m[3] * sm[k + 3];
    }
    sm[512 + tid] = s;
    __syncthreads();
    if (tid < 64)
        out[r0 + tid] = sm[512 + tid] + sm[512 + tid + 64] + sm[512 + tid + 128] +
                        sm[512 + tid + 192] + add1[r0 + tid] + add2[r0 + tid];
}

__global__ __launch_bounds__(256)
void prep_cvt(const float* __restrict__ text, const float* __restrict__ num,
              const float* __restrict__ tp_w, const float* __restrict__ np_w,
              const float* __restrict__ g_w, const float* __restrict__ m1_w,
              const float* __restrict__ m2_w,
              const float* __restrict__ a1_wv, const float* __restrict__ a2_wv,
              const float* __restrict__ a1_wo, const float* __restrict__ a2_wo,
              const float* __restrict__ a1_bv, const float* __restrict__ a1_bo,
              const float* __restrict__ a2_bv, const float* __restrict__ a2_bo,
              const float* __restrict__ tp_b, const float* __restrict__ np_b,
              u16* __restrict__ EMBc, u16* __restrict__ Wbig,
              u16* __restrict__ g_bf, u16* __restrict__ m1_bf, u16* __restrict__ m2_bf,
              u16* __restrict__ a1_wvT, u16* __restrict__ a2_wvT,
              u16* __restrict__ tp_wT, u16* __restrict__ np_wT,
              u16* __restrict__ a1_wo_bf, u16* __restrict__ a2_wo_bf,
              float* __restrict__ w1, float* __restrict__ w2,
              float* __restrict__ zb)
{
    __shared__ float smem[64 * 65];
    const int b = blockIdx.x, tid = threadIdx.x;
    if (b < 4096) {                       // EMBc[row,0:256]=text, [256:512]=num
#pragma unroll
        for (int c = 0; c < 2; ++c) {
            const int q = b * 512 + tid + 256 * c;
            const int e = q * 4, row = e >> 9, col = e & 511;
            const float* src = (col < 256) ? text + (size_t)row * 256 + col
                                           : num + (size_t)row * 256 + (col - 256);
            f32x4 v = *(const f32x4*)src;
            s16x4 o;
            o[0] = (short)f2b(v[0]); o[1] = (short)f2b(v[1]);
            o[2] = (short)f2b(v[2]); o[3] = (short)f2b(v[3]);
            *(s16x4*)(EMBc + e) = o;
        }
    } else if (b < 4352) { cvt_quads(g_w, g_bf, b - 4096, tid); }
    else if (b < 4608) { cvt_quads(m1_w, m1_bf, b - 4352, tid); }
    else if (b < 4672) { cvt_quads(m2_w, m2_bf, b - 4608, tid); }
    else if (b < 4736) {                  // np_w -> Wbig[0:512, 256:512]
#pragma unroll
        for (int c = 0; c < 2; ++c) {
            const int q = (b - 4672) * 512 + tid + 256 * c;
            const int e = q * 4, row = e >> 8, col = e & 255;
            f32x4 v = *(const f32x4*)(np_w + e);
            s16x4 o;
            o[0] = (short)f2b(v[0]); o[1] = (short)f2b(v[1]);
            o[2] = (short)f2b(v[2]); o[3] = (short)f2b(v[3]);
            *(s16x4*)(Wbig + (size_t)row * 512 + 256 + col) = o;
        }
    } else if (b < 4800) {                // tp_w -> Wbig[512:1024, 0:256]
#pragma unroll
        for (int c = 0; c < 2; ++c) {
            const int q = (b - 4736) * 512 + tid + 256 * c;
            const int e = q * 4, row = e >> 8, col = e & 255;
            f32x4 v = *(const f32x4*)(tp_w + e);
            s16x4 o;
            o[0] = (short)f2b(v[0]); o[1] = (short)f2b(v[1]);
            o[2] = (short)f2b(v[2]); o[3] = (short)f2b(v[3]);
            *(s16x4*)(Wbig + (size_t)(512 + row) * 512 + col) = o;
        }
    } else if (b < 4864) {
        const int t = b - 4800;
        transpose_cvt64(a1_wv, 512, a1_wvT, 512, (t >> 3) * 64, (t & 7) * 64, tid, smem);
    } else if (b < 4928) {
        const int t = b - 4864;
        transpose_cvt64(a2_wv, 512, a2_wvT, 512, (t >> 3) * 64, (t & 7) * 64, tid, smem);
    } else if (b < 4960) {
        const int t = b - 4928;
        transpose_cvt64(tp_w, 256, tp_wT, 512, (t >> 2) * 64, (t & 3) * 64, tid, smem);
    } else if (b < 4992) {
        const int t = b - 4960;
        transpose_cvt64(np_w, 256, np_wT, 512, (t >> 2) * 64, (t & 3) * 64, tid, smem);
    } else if (b < 5120) { cvt_quads(a1_wo, a1_wo_bf, b - 4992, tid); }
    else if (b < 5248) { cvt_quads(a2_wo, a2_wo_bf, b - 5120, tid); }
    else if (b < 5256) {
        matvec_rows(a1_wo, a1_bv, a1_bo, np_b, w1, (b - 5248) * 64, tid, smem);
    } else if (b < 5264) {
        matvec_rows(a2_wo, a2_bv, a2_bo, tp_b, w2, (b - 5256) * 64, tid, smem);
    } else {
        *(f32x4*)&zb[tid * 4] = f32x4{0.f, 0.f, 0.f, 0.f};
    }
}

__global__ __launch_bounds__(256)
void prep_bias(const u16* __restrict__ M1, const u16* __restrict__ M2,
               const float* __restrict__ tp_b, const float* __restrict__ np_b,
               const float* __restrict__ w1, const float* __restrict__ w2,
               float* __restrict__ bbig)
{
    __shared__ float sm[768];
    const int b = blockIdx.x, tid = threadIdx.x;
    const int side = b >> 3, r0 = (b & 7) * 64;
    const u16* M = side ? M2 : M1;
    const float* v = side ? np_b : tp_b;
    const float* w = side ? w2 : w1;
    float* out = bbig + side * 512;
    for (int i = tid; i < 512; i += 256) sm[i] = v[i];
    __syncthreads();
    const int row = r0 + (tid & 63), q = tid >> 6;
    float s = 0.f;
    for (int k = q * 128; k < q * 128 + 128; k += 8) {
        s16x8 m = *(const s16x8*)&M[(size_t)row * 512 + k];
#pragma unroll
        for (int j = 0; j < 8; ++j) s += b2f((u16)m[j]) * sm[k + j];
    }
    sm[512 + tid] = s;
    __syncthreads();
    if (tid < 64)
        out[r0 + tid] = sm[512 + tid] + sm[512 + tid + 64] + sm[512 + tid + 128] +
                        sm[512 + tid + 192] + w[r0 + tid];
}

extern "C" void kernel_launch(void* const* d_in, const int* in_sizes, int n_in,
                              void* d_out, int out_size, void* d_ws, size_t ws_size,
                              hipStream_t stream)
{
    const float* text  = (const float*)d_in[0];
    const float* num   = (const float*)d_in[1];
    const float* tp_w  = (const float*)d_in[2];
    const float* tp_b  = (const float*)d_in[3];
    const float* np_w  = (const float*)d_in[4];
    const float* np_b  = (const float*)d_in[5];
    const float* a1_wv = (const float*)d_in[8];
    const float* a1_bv = (const float*)d_in[11];
    const float* a1_wo = (const float*)d_in[12];
    const float* a1_bo = (const float*)d_in[13];
    const float* a2_wv = (const float*)d_in[16];
    const float* a2_bv = (const float*)d_in[19];
    const float* a2_wo = (const float*)d_in[20];
    const float* a2_bo = (const float*)d_in[21];
    const float* n1_g  = (const float*)d_in[22];
    const float* n1_b  = (const float*)d_in[23];
    const float* n2_g  = (const float*)d_in[24];
    const float* n2_b  = (const float*)d_in[25];
    const float* g_w   = (const float*)d_in[26];
    const float* g_b   = (const float*)d_in[27];
    const float* m1_w  = (const float*)d_in[28];
    const float* m1_b  = (const float*)d_in[29];
    const float* ln1_g = (const float*)d_in[30];
    const float* ln1_b = (const float*)d_in[31];
    const float* m2_w  = (const float*)d_in[32];
    const float* m2_b  = (const float*)d_in[33];
    const float* ln2_g = (const float*)d_in[34];
    const float* ln2_b = (const float*)d_in[35];

    float* outp = (float*)d_out;
    char* ob = (char*)d_out;
    char* ws = (char*)d_ws;
    const size_t KB = 1024, MB = 1048576;

    // ws: comb [0,32MB), h [32,48MB), weight scratch [48MB,...)
    u16* comb = (u16*)ws;                            // [16384 x 1024] bf16
    u16* h    = (u16*)(ws + 32 * MB);                // [16384 x 512] bf16
    char* sc  = ws + 48 * MB;
    u16* Wbig     = (u16*)(sc);                      // 1 MB [1024x512]
    u16* g_bf     = (u16*)(sc + 1 * MB);             // 1 MB [512x1024]
    u16* m1_bf    = (u16*)(sc + 2 * MB);             // 1 MB [512x1024]
    u16* m2_bf    = (u16*)(sc + 3 * MB);             // 256 KB [256x512]
    u16* a1_wvT   = (u16*)(sc + 3 * MB + 256 * KB);  // 512 KB
    u16* a2_wvT   = (u16*)(sc + 3 * MB + 768 * KB);  // 512 KB
    u16* tp_wT    = (u16*)(sc + 4 * MB + 256 * KB);  // 256 KB [256x512]
    u16* np_wT    = (u16*)(sc + 4 * MB + 512 * KB);  // 256 KB
    u16* a1_wo_bf = (u16*)(sc + 4 * MB + 768 * KB);  // 512 KB
    u16* a2_wo_bf = (u16*)(sc + 5 * MB + 256 * KB);  // 512 KB
    u16* M1       = (u16*)(sc + 5 * MB + 768 * KB);  // 512 KB
    u16* M2       = (u16*)(sc + 6 * MB + 256 * KB);  // 512 KB
    float* w1     = (float*)(sc + 6 * MB + 768 * KB);
    float* w2     = w1 + 512;
    float* bbig   = w1 + 1024;
    float* zb     = w1 + 2048;
    // d_out scratch: EMBc in the dead gate byte-range [16MB,32MB)
    u16* EMBc = (u16*)(ob + 16 * MB);                // [16384 x 512] bf16

    float* gate_out = outp + (size_t)16384 * 256;    // [B,512] f32
    float* attn1 = outp + (size_t)16384 * 768;
    float* attn2 = outp + (size_t)16384 * 768 + 16384;

    dim3 blk(256);

    // P1: conversions, transposes, w1/w2, zbias
    prep_cvt<<<5265, blk, 0, stream>>>(text, num, tp_w, np_w, g_w, m1_w, m2_w,
        a1_wv, a2_wv, a1_wo, a2_wo, a1_bv, a1_bo, a2_bv, a2_bo, tp_b, np_b,
        EMBc, Wbig, g_bf, m1_bf, m2_bf, a1_wvT, a2_wvT, tp_wT, np_wT,
        a1_wo_bf, a2_wo_bf, w1, w2, zb);
    // F1: M1 = a1_wo@a1_wv ; M2 = a2_wo@a2_wv
    gemm_bt<2><<<dim3(4, 4), blk, 0, stream>>>(a1_wo_bf, a2_wo_bf, a1_wvT, a2_wvT,
        zb, zb, M1, M2, 512, 512, 2, 512, 512, 0, 0);
    // PB: bbig = [M1@tp_b + w1 | M2@np_b + w2]
    prep_bias<<<16, blk, 0, stream>>>(M1, M2, tp_b, np_b, w1, w2, bbig);
    // F2: Wbig[0:512,0:256] = M1@tp_w ; Wbig[512:,256:] = M2@np_w
    gemm_bt<2><<<dim3(2, 4), blk, 0, stream>>>(M1, M2, tp_wT, np_wT,
        zb, zb, Wbig, Wbig + (size_t)512 * 512 + 256, 512, 512, 1, 512, 512, 0, 0);
    // G1': comb = [LN(EMB@WbigL.T + bL)*n1 | LN(EMB@WbigR.T + bR)*n2]
    gemm_ln<8><<<dim3(2, 128), dim3(512), 0, stream>>>(EMBc, EMBc,
        Wbig, Wbig + (size_t)512 * 512, bbig, bbig + 512,
        n1_g, n2_g, n1_b, n2_b, comb, comb + 512,
        512, 512, 1, 1024, 1024, 0, 0, nullptr, nullptr);
    // G2': gate = sigmoid(comb@g_w.T+g_b) f32 ; h = gelu(LN(comb@m1_w.T+m1_b)*ln1)
    gemm_ln<8><<<dim3(2, 128), dim3(512), 0, stream>>>(comb, comb, g_bf, m1_bf,
        g_b, m1_b, ln1_g, ln1_g, ln1_b, ln1_b, gate_out, h,
        1024, 1024, 1, 512, 512, 2, 1, nullptr, nullptr);
    // G3': fused = gelu(LN(h@m2_w.T+m2_b)*ln2) f32 -> d_out; attn := 1.0
    gemm_ln<4><<<dim3(1, 128), dim3(512), 0, stream>>>(h, h, m2_bf, m2_bf,
        m2_b, m2_b, ln2_g, ln2_g, ln2_b, ln2_b, outp, outp,
        512, 512, 1, 256, 256, 3, 3, attn1, attn2);
}